// Round 2
// baseline (3035.595 us; speedup 1.0000x reference)
//
#include <hip/hip_runtime.h>
#include <stdint.h>

#define N_ROWS 8192
#define D 384
#define K_CODES 25000
#define ROWS_T 64
#define KT 64
#define KSPLIT 4
#define KPER 6250   // 25000/4
#define NKT 98      // ceil(6250/64)

// ---------------- Kernel 1: init argmin keys + row sum of squares --------------------
// Note: exact summation order of s is argmin-invariant (uniform grid shift within the
// binade), but we keep the numpy-like pairwise order anyway.
__global__ __launch_bounds__(256) void prep_kernel(const float* __restrict__ feat,
                                                   unsigned long long* __restrict__ keys,
                                                   float* __restrict__ S)
{
#pragma clang fp contract(off)
    int row = blockIdx.x * 256 + threadIdx.x;
    if (row >= N_ROWS) return;
    keys[row] = ~0ULL;
    const float* x = feat + (size_t)row * D;
    float Bres[4];
#pragma unroll
    for (int b = 0; b < 4; ++b) {
        const float* q = x + b * 96;
        float v[8][4];
#pragma unroll
        for (int j = 0; j < 8; ++j)
#pragma unroll
            for (int l = 0; l < 4; ++l) {
                float t = q[4 * j + l];
                v[j][l] = t * t;                 // product rounded separately (contract off)
            }
#pragma unroll
        for (int i = 32; i <= 64; i += 32)
#pragma unroll
            for (int j = 0; j < 8; ++j)
#pragma unroll
                for (int l = 0; l < 4; ++l) {
                    float t = q[i + 4 * j + l];
                    float p = t * t;
                    v[j][l] = v[j][l] + p;
                }
        float c[4];
#pragma unroll
        for (int l = 0; l < 4; ++l)
            c[l] = ((v[0][l] + v[1][l]) + (v[2][l] + v[3][l]))
                 + ((v[4][l] + v[5][l]) + (v[6][l] + v[7][l]));
        Bres[b] = (c[0] + c[1]) + (c[2] + c[3]);
    }
    S[row] = (Bres[0] + Bres[1]) + (Bres[2] + Bres[3]);
}

// ---------------- Kernel 2: tiled fp32 GEMM + fused argmin --------------------------
// grid = 128 row-tiles x 4 K-splits = 512 blocks, 256 threads.
// Thread (tr=tid&15, tk=tid>>4) owns rows 4tr..4tr+3 x codes 4tk..4tk+3 per tile.
// LDS float4 tiles swizzled: physical col = logical col ^ ((row>>2)&7). For the
// read of row 4*tk+i the de-swizzle is therefore dk4 ^ (tk & 7)  [bug fixed: was ^tk].
__global__ __launch_bounds__(256) void gemm_argmin_kernel(const float* __restrict__ feat,
                                                          const float* __restrict__ cb,
                                                          const float* __restrict__ S,
                                                          unsigned long long* __restrict__ keys)
{
    __shared__ float4 A4[ROWS_T][16];
    __shared__ float4 B4[KT][16];

    const int tid = threadIdx.x;
    const int tr = tid & 15;
    const int tk = tid >> 4;
    const int rt = blockIdx.x & 127;
    const int ks = blockIdx.x >> 7;
    const int r0 = rt * ROWS_T;
    const int kbase = ks * KPER;

    float s_reg[4];
#pragma unroll
    for (int i = 0; i < 4; ++i) s_reg[i] = S[r0 + 4 * tr + i];

    unsigned long long best[4];
#pragma unroll
    for (int i = 0; i < 4; ++i) best[i] = ~0ULL;

    for (int kt = 0; kt < NKT; ++kt) {
        const int k0 = kbase + kt * KT;
        float acc[4][4];
#pragma unroll
        for (int ii = 0; ii < 4; ++ii)
#pragma unroll
            for (int jj = 0; jj < 4; ++jj) acc[ii][jj] = 0.f;

        for (int dc = 0; dc < 6; ++dc) {
            __syncthreads();
#pragma unroll
            for (int t = 0; t < 4; ++t) {
                int fidx = t * 256 + tid;   // 0..1023
                int r = fidx >> 4;
                int c4 = fidx & 15;
                const float4* asrc =
                    reinterpret_cast<const float4*>(feat + (size_t)(r0 + r) * D + dc * 64);
                A4[r][c4 ^ ((r >> 2) & 7)] = asrc[c4];
                int k = k0 + r;
                float4 bval = make_float4(0.f, 0.f, 0.f, 0.f);
                if (k < K_CODES) {
                    const float4* bsrc =
                        reinterpret_cast<const float4*>(cb + (size_t)k * D + dc * 64);
                    bval = bsrc[c4];
                }
                B4[r][c4 ^ ((r >> 2) & 7)] = bval;
            }
            __syncthreads();
#pragma unroll 4
            for (int dk4 = 0; dk4 < 16; ++dk4) {
                float4 av[4], bv[4];
#pragma unroll
                for (int i = 0; i < 4; ++i) av[i] = A4[4 * tr + i][dk4 ^ (tr & 7)];
#pragma unroll
                for (int i = 0; i < 4; ++i) bv[i] = B4[4 * tk + i][dk4 ^ (tk & 7)];
#pragma unroll
                for (int ri = 0; ri < 4; ++ri)
#pragma unroll
                    for (int ki = 0; ki < 4; ++ki) {
                        acc[ri][ki] = fmaf(av[ri].x, bv[ki].x, acc[ri][ki]);
                        acc[ri][ki] = fmaf(av[ri].y, bv[ki].y, acc[ri][ki]);
                        acc[ri][ki] = fmaf(av[ri].z, bv[ki].z, acc[ri][ki]);
                        acc[ri][ki] = fmaf(av[ri].w, bv[ki].w, acc[ri][ki]);
                    }
            }
        }
#pragma unroll
        for (int ri = 0; ri < 4; ++ri) {
#pragma unroll
            for (int ki = 0; ki < 4; ++ki) {
                int k = k0 + 4 * tk + ki;
                if (k < K_CODES) {
                    float d = s_reg[ri] - 2.0f * acc[ri][ki];
                    unsigned int bits = __float_as_uint(d);
                    bits = bits ^ ((bits & 0x80000000u) ? 0xFFFFFFFFu : 0x80000000u);
                    unsigned long long key =
                        ((unsigned long long)bits << 32) | (unsigned long long)(unsigned)k;
                    best[ri] = key < best[ri] ? key : best[ri];
                }
            }
        }
    }
#pragma unroll
    for (int ri = 0; ri < 4; ++ri)
        atomicMin(&keys[r0 + 4 * tr + ri], best[ri]);
}

// ---------------- Kernel 3: keys -> token ids (as float values) ----------------------
__global__ __launch_bounds__(256) void finalize_kernel(const unsigned long long* __restrict__ keys,
                                                       float* __restrict__ out)
{
    int r = blockIdx.x * 256 + threadIdx.x;
    if (r < N_ROWS) out[r] = (float)(unsigned int)(keys[r] & 0xFFFFFFFFULL);
}

// ---------------- Kernel 4: features passthrough ------------------------------------
__global__ __launch_bounds__(256) void copyfeat_kernel(const float4* __restrict__ src,
                                                       float4* __restrict__ dst, int n4)
{
    int i = blockIdx.x * 256 + threadIdx.x;
    if (i < n4) dst[i] = src[i];
}

extern "C" void kernel_launch(void* const* d_in, const int* in_sizes, int n_in,
                              void* d_out, int out_size, void* d_ws, size_t ws_size,
                              hipStream_t stream)
{
    const float* feat = (const float*)d_in[0];   // [8192, 384]
    const float* cb   = (const float*)d_in[1];   // [25000, 384]
    float* out = (float*)d_out;                  // [8192 ids][8192*384 features]

    unsigned long long* keys = (unsigned long long*)d_ws;          // 8192 * 8 B
    float* S = (float*)((char*)d_ws + (size_t)N_ROWS * 8);         // 8192 * 4 B

    prep_kernel<<<N_ROWS / 256, 256, 0, stream>>>(feat, keys, S);
    gemm_argmin_kernel<<<(N_ROWS / ROWS_T) * KSPLIT, 256, 0, stream>>>(feat, cb, S, keys);
    finalize_kernel<<<N_ROWS / 256, 256, 0, stream>>>(keys, out);
    copyfeat_kernel<<<(N_ROWS * D / 4) / 256, 256, 0, stream>>>(
        (const float4*)feat, (float4*)(out + N_ROWS), N_ROWS * D / 4);
}

// Round 3
// 689.930 us; speedup vs baseline: 4.3999x; 4.3999x over previous
//
#include <hip/hip_runtime.h>
#include <stdint.h>

#define N_ROWS 8192
#define D 384
#define K_CODES 25000

typedef __attribute__((ext_vector_type(8))) short bf16x8;
typedef __attribute__((ext_vector_type(4))) float f32x4;

// ---- fast-path ws layout (bytes) ----
#define WS_XB    0ULL                          // 8192*384*2   = 6291456
#define WS_CBB   6291456ULL                    // 25000*384*2  = 19200000
#define WS_CAND  25491456ULL                   // 8192*96*4    = 3145728
#define WS_KEYS  28637184ULL                   // 8192*8       = 65536
#define WS_FKEY  28702720ULL                   // 8192*8       = 65536
#define WS_S     28768256ULL                   // 8192*4       = 32768
#define WS_MG    28801024ULL                   // 8192*4       = 32768
#define WS_CNT   28833792ULL                   // 8192*4       = 32768
#define WS_NEED  28866560ULL

__device__ __forceinline__ unsigned int mono_bits(float f) {
    unsigned int u = __float_as_uint(f);
    return u ^ ((u & 0x80000000u) ? 0xFFFFFFFFu : 0x80000000u);
}
__device__ __forceinline__ float unmono_bits(unsigned int m) {
    unsigned int u = (m & 0x80000000u) ? (m ^ 0x80000000u) : ~m;
    return __uint_as_float(u);
}
__device__ __forceinline__ unsigned short f2bf_rne(float f) {
    unsigned int u = __float_as_uint(f);
    return (unsigned short)((u + 0x7FFFu + ((u >> 16) & 1u)) >> 16);
}

// ---------------- fp32 -> bf16 conversion (vectorized) -------------------------------
__global__ __launch_bounds__(256) void cvt_bf16_kernel(const float4* __restrict__ src,
                                                       ushort4* __restrict__ dst, int n4)
{
    int i = blockIdx.x * 256 + threadIdx.x;
    if (i >= n4) return;
    float4 v = src[i];
    ushort4 o;
    o.x = f2bf_rne(v.x); o.y = f2bf_rne(v.y); o.z = f2bf_rne(v.z); o.w = f2bf_rne(v.w);
    dst[i] = o;
}

// ---------------- prep: S (numpy-order, bit-identical to round-2), margin, init ------
__global__ __launch_bounds__(256) void prep_kernel(const float* __restrict__ feat,
                                                   unsigned long long* __restrict__ keys,
                                                   float* __restrict__ S,
                                                   float* __restrict__ Mg,
                                                   unsigned int* __restrict__ cnt)
{
#pragma clang fp contract(off)
    int row = blockIdx.x * 256 + threadIdx.x;
    if (row >= N_ROWS) return;
    keys[row] = ~0ULL;
    if (cnt) cnt[row] = 0u;
    const float* x = feat + (size_t)row * D;
    float Bres[4];
#pragma unroll
    for (int b = 0; b < 4; ++b) {
        const float* q = x + b * 96;
        float v[8][4];
#pragma unroll
        for (int j = 0; j < 8; ++j)
#pragma unroll
            for (int l = 0; l < 4; ++l) {
                float t = q[4 * j + l];
                v[j][l] = t * t;
            }
#pragma unroll
        for (int i = 32; i <= 64; i += 32)
#pragma unroll
            for (int j = 0; j < 8; ++j)
#pragma unroll
                for (int l = 0; l < 4; ++l) {
                    float t = q[i + 4 * j + l];
                    float p = t * t;
                    v[j][l] = v[j][l] + p;
                }
        float c[4];
#pragma unroll
        for (int l = 0; l < 4; ++l)
            c[l] = ((v[0][l] + v[1][l]) + (v[2][l] + v[3][l]))
                 + ((v[4][l] + v[5][l]) + (v[6][l] + v[7][l]));
        Bres[b] = (c[0] + c[1]) + (c[2] + c[3]);
    }
    float s = (Bres[0] + Bres[1]) + (Bres[2] + Bres[3]);
    S[row] = s;
    if (Mg) Mg[row] = scalbnf(1.0f, ilogbf(s) - 23) + 1.2e-4f;  // ulp(s) + 17-sigma slack
}

// ---------------- bf16 MFMA GEMM + approx argmin + candidate collection --------------
// grid: (196 n-tiles) x (64 row-tiles); block 256 = 4 waves (2x2 wave grid of 64x64).
// LDS tiles [128 rows][64 bf16], 16B-chunk XOR swizzle (chunk ^= row&7), staged via
// global_load_lds(16B) with pre-swizzled per-lane global source (T2/m201 pattern).
__global__ __launch_bounds__(256) void mfma_gemm_argmin(const ushort* __restrict__ xb,
                                                        const ushort* __restrict__ cbb,
                                                        const float* __restrict__ Mg,
                                                        unsigned long long* __restrict__ keys,
                                                        unsigned int* __restrict__ cnt,
                                                        unsigned int* __restrict__ cand,
                                                        int do_append)
{
    __shared__ ushort At[128 * 64];
    __shared__ ushort Bt[128 * 64];
    __shared__ float Mrow_s[128];

    const int tid = threadIdx.x;
    const int rt = blockIdx.x & 63;
    const int nt = blockIdx.x >> 6;
    const int r0 = rt * 128;
    const int n0 = nt * 128;
    const int wave = tid >> 6;
    const int lane = tid & 63;
    const int ln15 = lane & 15;
    const int l16 = lane >> 4;
    const int wm = (wave >> 1) * 64;
    const int wn = (wave & 1) * 64;

    if (tid < 128) Mrow_s[tid] = Mg[r0 + tid];

    f32x4 acc[4][4] = {};

    for (int kt = 0; kt < 6; ++kt) {
        __syncthreads();   // protect LDS reuse (also covers Mrow_s visibility on kt=0)
#pragma unroll
        for (int q = 0; q < 4; ++q) {
            int s = q * 256 + tid;          // 16B slot 0..1023
            int r = s >> 3;                 // tile row
            int pc = s & 7;                 // physical chunk
            int lc = pc ^ (r & 7);          // logical chunk fetched into this slot
            const ushort* ga = xb + (size_t)(r0 + r) * D + kt * 64 + lc * 8;
            __builtin_amdgcn_global_load_lds(
                (const __attribute__((address_space(1))) void*)ga,
                (__attribute__((address_space(3))) void*)&At[s * 8], 16, 0, 0);
            int code = n0 + r;
            if (code > K_CODES - 1) code = K_CODES - 1;   // clamp; masked in epilogue
            const ushort* gb = cbb + (size_t)code * D + kt * 64 + lc * 8;
            __builtin_amdgcn_global_load_lds(
                (const __attribute__((address_space(1))) void*)gb,
                (__attribute__((address_space(3))) void*)&Bt[s * 8], 16, 0, 0);
        }
        __syncthreads();   // compiler drains vmcnt before barrier
#pragma unroll
        for (int ks = 0; ks < 2; ++ks) {
            bf16x8 af[4], bfr[4];
#pragma unroll
            for (int mi = 0; mi < 4; ++mi) {
                int r = wm + mi * 16 + ln15;
                int lc = ks * 4 + l16;
                af[mi] = *(const bf16x8*)&At[r * 64 + ((lc ^ (r & 7)) << 3)];
            }
#pragma unroll
            for (int ni = 0; ni < 4; ++ni) {
                int r = wn + ni * 16 + ln15;
                int lc = ks * 4 + l16;
                bfr[ni] = *(const bf16x8*)&Bt[r * 64 + ((lc ^ (r & 7)) << 3)];
            }
#pragma unroll
            for (int mi = 0; mi < 4; ++mi)
#pragma unroll
                for (int ni = 0; ni < 4; ++ni)
                    acc[mi][ni] = __builtin_amdgcn_mfma_f32_16x16x32_bf16(
                        af[mi], bfr[ni], acc[mi][ni], 0, 0, 0);
        }
    }

    // epilogue: v = -2*m_approx; wave-local per-row min -> atomicMin; append within margin
#pragma unroll
    for (int mi = 0; mi < 4; ++mi) {
#pragma unroll
        for (int rr = 0; rr < 4; ++rr) {
            int rloc = wm + mi * 16 + l16 * 4 + rr;
            int row = r0 + rloc;
            float v[4];
            unsigned long long kmin = ~0ULL;
#pragma unroll
            for (int ni = 0; ni < 4; ++ni) {
                int n = n0 + wn + ni * 16 + ln15;
                float vv = -2.0f * acc[mi][ni][rr];
                bool ok = (n < K_CODES);
                v[ni] = ok ? vv : __int_as_float(0x7F800000);
                if (ok) {
                    unsigned long long key =
                        ((unsigned long long)mono_bits(vv) << 32) | (unsigned)n;
                    kmin = key < kmin ? key : kmin;
                }
            }
#pragma unroll
            for (int off = 1; off < 16; off <<= 1) {
                unsigned long long o = __shfl_xor(kmin, off);
                kmin = o < kmin ? o : kmin;
            }
            unsigned long long old = ~0ULL;
            if (ln15 == 0 && kmin != ~0ULL) old = atomicMin(&keys[row], kmin);
            old = __shfl(old, lane & 48);        // broadcast from group's ln15==0 lane
            unsigned long long g = old < kmin ? old : kmin;
            if (do_append) {
                float vthresh = unmono_bits((unsigned int)(g >> 32)) + Mrow_s[rloc];
#pragma unroll
                for (int ni = 0; ni < 4; ++ni) {
                    int n = n0 + wn + ni * 16 + ln15;
                    if (n < K_CODES && v[ni] <= vthresh) {
                        unsigned int idx = atomicAdd(&cnt[row], 1u);
                        if (idx < 96u) cand[(size_t)row * 96 + idx] = (unsigned int)n;
                    }
                }
            }
        }
    }
}

// ---------------- exact fp32 rescore of candidates (round-2 chain order) -------------
__global__ __launch_bounds__(256) void rescore_kernel(const float* __restrict__ feat,
                                                      const float* __restrict__ cb,
                                                      const float* __restrict__ S,
                                                      const unsigned int* __restrict__ cnt,
                                                      const unsigned int* __restrict__ cand,
                                                      unsigned long long* __restrict__ fkey)
{
    int row = blockIdx.x * 4 + (threadIdx.x >> 6);
    int lane = threadIdx.x & 63;
    unsigned int c = cnt[row];
    if (c > 96u) return;                     // rescue kernel owns this row
    const float* x = feat + (size_t)row * D;
    float s = S[row];
    unsigned long long best = ~0ULL;
#pragma unroll
    for (int base = 0; base < 96; base += 64) {
        int ci = base + lane;
        if (ci < (int)c) {
            unsigned int n = cand[(size_t)row * 96 + ci];
            const float* cr = cb + (size_t)n * D;
            float m = 0.f;
            for (int d = 0; d < D; ++d) m = fmaf(x[d], cr[d], m);
            float dd = s - 2.0f * m;
            unsigned long long key =
                ((unsigned long long)mono_bits(dd) << 32) | n;
            best = key < best ? key : best;
        }
    }
#pragma unroll
    for (int off = 1; off < 64; off <<= 1) {
        unsigned long long o = __shfl_xor(best, off);
        best = o < best ? o : best;
    }
    if (lane == 0) fkey[row] = best;
}

// ---------------- rescue: full exact scan for overflowed rows (expected: none) -------
__global__ __launch_bounds__(256) void rescue_kernel(const float* __restrict__ feat,
                                                     const float* __restrict__ cb,
                                                     const float* __restrict__ S,
                                                     const unsigned int* __restrict__ cnt,
                                                     unsigned long long* __restrict__ fkey)
{
    __shared__ unsigned long long red[256];
    for (int row = blockIdx.x; row < N_ROWS; row += gridDim.x) {
        if (cnt[row] <= 96u) continue;
        const float* x = feat + (size_t)row * D;
        float s = S[row];
        unsigned long long best = ~0ULL;
        for (int n = threadIdx.x; n < K_CODES; n += 256) {
            const float* cr = cb + (size_t)n * D;
            float m = 0.f;
            for (int d = 0; d < D; ++d) m = fmaf(x[d], cr[d], m);
            float dd = s - 2.0f * m;
            unsigned long long key = ((unsigned long long)mono_bits(dd) << 32) | (unsigned)n;
            best = key < best ? key : best;
        }
        red[threadIdx.x] = best;
        __syncthreads();
        for (int st = 128; st > 0; st >>= 1) {
            if (threadIdx.x < st)
                if (red[threadIdx.x + st] < red[threadIdx.x]) red[threadIdx.x] = red[threadIdx.x + st];
            __syncthreads();
        }
        if (threadIdx.x == 0) fkey[row] = red[0];
        __syncthreads();
    }
}

// ---------------- fallback (round-2 proven fp32 path) --------------------------------
__global__ __launch_bounds__(256) void gemm_argmin_fb(const float* __restrict__ feat,
                                                      const float* __restrict__ cb,
                                                      const float* __restrict__ S,
                                                      unsigned long long* __restrict__ keys)
{
    __shared__ float4 A4[64][16];
    __shared__ float4 B4[64][16];
    const int tid = threadIdx.x;
    const int tr = tid & 15;
    const int tk = tid >> 4;
    const int rt = blockIdx.x & 127;
    const int ks = blockIdx.x >> 7;
    const int r0 = rt * 64;
    const int kbase = ks * 6250;
    float s_reg[4];
#pragma unroll
    for (int i = 0; i < 4; ++i) s_reg[i] = S[r0 + 4 * tr + i];
    unsigned long long best[4];
#pragma unroll
    for (int i = 0; i < 4; ++i) best[i] = ~0ULL;
    for (int kt = 0; kt < 98; ++kt) {
        const int k0 = kbase + kt * 64;
        float acc[4][4];
#pragma unroll
        for (int ii = 0; ii < 4; ++ii)
#pragma unroll
            for (int jj = 0; jj < 4; ++jj) acc[ii][jj] = 0.f;
        for (int dc = 0; dc < 6; ++dc) {
            __syncthreads();
#pragma unroll
            for (int t = 0; t < 4; ++t) {
                int fidx = t * 256 + tid;
                int r = fidx >> 4;
                int c4 = fidx & 15;
                const float4* asrc = reinterpret_cast<const float4*>(feat + (size_t)(r0 + r) * D + dc * 64);
                A4[r][c4 ^ ((r >> 2) & 7)] = asrc[c4];
                int k = k0 + r;
                float4 bval = make_float4(0.f, 0.f, 0.f, 0.f);
                if (k < K_CODES) {
                    const float4* bsrc = reinterpret_cast<const float4*>(cb + (size_t)k * D + dc * 64);
                    bval = bsrc[c4];
                }
                B4[r][c4 ^ ((r >> 2) & 7)] = bval;
            }
            __syncthreads();
#pragma unroll 4
            for (int dk4 = 0; dk4 < 16; ++dk4) {
                float4 av[4], bv[4];
#pragma unroll
                for (int i = 0; i < 4; ++i) av[i] = A4[4 * tr + i][dk4 ^ (tr & 7)];
#pragma unroll
                for (int i = 0; i < 4; ++i) bv[i] = B4[4 * tk + i][dk4 ^ (tk & 7)];
#pragma unroll
                for (int ri = 0; ri < 4; ++ri)
#pragma unroll
                    for (int ki = 0; ki < 4; ++ki) {
                        acc[ri][ki] = fmaf(av[ri].x, bv[ki].x, acc[ri][ki]);
                        acc[ri][ki] = fmaf(av[ri].y, bv[ki].y, acc[ri][ki]);
                        acc[ri][ki] = fmaf(av[ri].z, bv[ki].z, acc[ri][ki]);
                        acc[ri][ki] = fmaf(av[ri].w, bv[ki].w, acc[ri][ki]);
                    }
            }
        }
#pragma unroll
        for (int ri = 0; ri < 4; ++ri)
#pragma unroll
            for (int ki = 0; ki < 4; ++ki) {
                int k = k0 + 4 * tk + ki;
                if (k < K_CODES) {
                    float d = s_reg[ri] - 2.0f * acc[ri][ki];
                    unsigned long long key =
                        ((unsigned long long)mono_bits(d) << 32) | (unsigned long long)(unsigned)k;
                    best[ri] = key < best[ri] ? key : best[ri];
                }
            }
    }
#pragma unroll
    for (int ri = 0; ri < 4; ++ri)
        atomicMin(&keys[r0 + 4 * tr + ri], best[ri]);
}

// ---------------- output kernels ------------------------------------------------------
__global__ __launch_bounds__(256) void finalize_kernel(const unsigned long long* __restrict__ keys,
                                                       float* __restrict__ out)
{
    int r = blockIdx.x * 256 + threadIdx.x;
    if (r < N_ROWS) out[r] = (float)(unsigned int)(keys[r] & 0xFFFFFFFFULL);
}
__global__ __launch_bounds__(256) void copyfeat_kernel(const float4* __restrict__ src,
                                                       float4* __restrict__ dst, int n4)
{
    int i = blockIdx.x * 256 + threadIdx.x;
    if (i < n4) dst[i] = src[i];
}

extern "C" void kernel_launch(void* const* d_in, const int* in_sizes, int n_in,
                              void* d_out, int out_size, void* d_ws, size_t ws_size,
                              hipStream_t stream)
{
    const float* feat = (const float*)d_in[0];   // [8192, 384]
    const float* cb   = (const float*)d_in[1];   // [25000, 384]
    float* out = (float*)d_out;

    char* ws = (char*)d_ws;

    if (ws_size >= WS_NEED) {
        ushort* xb  = (ushort*)(ws + WS_XB);
        ushort* cbb = (ushort*)(ws + WS_CBB);
        unsigned int* cand = (unsigned int*)(ws + WS_CAND);
        unsigned long long* keys = (unsigned long long*)(ws + WS_KEYS);
        unsigned long long* fkey = (unsigned long long*)(ws + WS_FKEY);
        float* S  = (float*)(ws + WS_S);
        float* Mg = (float*)(ws + WS_MG);
        unsigned int* cnt = (unsigned int*)(ws + WS_CNT);

        cvt_bf16_kernel<<<3072, 256, 0, stream>>>((const float4*)feat, (ushort4*)xb,
                                                  N_ROWS * D / 4);
        cvt_bf16_kernel<<<9375, 256, 0, stream>>>((const float4*)cb, (ushort4*)cbb,
                                                  K_CODES * D / 4);
        prep_kernel<<<N_ROWS / 256, 256, 0, stream>>>(feat, keys, S, Mg, cnt);
        // seed pass: 8 n-tiles (codes 0..1023) warm the per-row global minima
        mfma_gemm_argmin<<<8 * 64, 256, 0, stream>>>(xb, cbb, Mg, keys, cnt, cand, 0);
        // main pass: all 196 n-tiles, with candidate collection
        mfma_gemm_argmin<<<196 * 64, 256, 0, stream>>>(xb, cbb, Mg, keys, cnt, cand, 1);
        rescore_kernel<<<N_ROWS / 4, 256, 0, stream>>>(feat, cb, S, cnt, cand, fkey);
        rescue_kernel<<<256, 256, 0, stream>>>(feat, cb, S, cnt, fkey);
        finalize_kernel<<<N_ROWS / 256, 256, 0, stream>>>(fkey, out);
    } else {
        // fallback: round-2 proven fp32 pipeline (keys at 0, S at 64KB)
        unsigned long long* keys = (unsigned long long*)ws;
        float* S = (float*)(ws + 65536);
        prep_kernel<<<N_ROWS / 256, 256, 0, stream>>>(feat, keys, S, nullptr, nullptr);
        gemm_argmin_fb<<<128 * 4, 256, 0, stream>>>(feat, cb, S, keys);
        finalize_kernel<<<N_ROWS / 256, 256, 0, stream>>>(keys, out);
    }
    copyfeat_kernel<<<(N_ROWS * D / 4) / 256, 256, 0, stream>>>(
        (const float4*)feat, (float4*)(out + N_ROWS), N_ROWS * D / 4);
}

// Round 4
// 382.680 us; speedup vs baseline: 7.9325x; 1.8029x over previous
//
#include <hip/hip_runtime.h>
#include <stdint.h>

#define N_ROWS 8192
#define D 384
#define K_CODES 25000
#define CAND_CAP 96

typedef __attribute__((ext_vector_type(8))) short bf16x8;
typedef __attribute__((ext_vector_type(4))) float f32x4;

// ---- ws layout (bytes) — total 28,866,560 == round-3 proven budget ----
#define WS_XB    0ULL                          // 8192*384*2   = 6291456
#define WS_CBB   6291456ULL                    // 25000*384*2  = 19200000
#define WS_CAND  25491456ULL                   // 8192*96*4    = 3145728
#define WS_FKEY  28637184ULL                   // 8192*8
#define WS_S     28702720ULL                   // 8192*4
#define WS_MG    28735488ULL                   // 8192*4
#define WS_THR   28768256ULL                   // 8192*4
#define WS_CNT   28801024ULL                   // 8192*4
#define WS_NEED  28833792ULL

__device__ __forceinline__ unsigned int mono_bits(float f) {
    unsigned int u = __float_as_uint(f);
    return u ^ ((u & 0x80000000u) ? 0xFFFFFFFFu : 0x80000000u);
}
__device__ __forceinline__ float unmono_bits(unsigned int m) {
    unsigned int u = (m & 0x80000000u) ? (m ^ 0x80000000u) : ~m;
    return __uint_as_float(u);
}
__device__ __forceinline__ unsigned short f2bf_rne(float f) {
    unsigned int u = __float_as_uint(f);
    return (unsigned short)((u + 0x7FFFu + ((u >> 16) & 1u)) >> 16);
}

// ---------------- fp32 -> bf16 conversion ---------------------------------------------
__global__ __launch_bounds__(256) void cvt_bf16_kernel(const float4* __restrict__ src,
                                                       ushort4* __restrict__ dst, int n4)
{
    int i = blockIdx.x * 256 + threadIdx.x;
    if (i >= n4) return;
    float4 v = src[i];
    ushort4 o;
    o.x = f2bf_rne(v.x); o.y = f2bf_rne(v.y); o.z = f2bf_rne(v.z); o.w = f2bf_rne(v.w);
    dst[i] = o;
}

// ---------------- prep: S (numpy pairwise order), margin, Thr/cnt init ----------------
__global__ __launch_bounds__(256) void prep_kernel(const float* __restrict__ feat,
                                                   float* __restrict__ S,
                                                   float* __restrict__ Mg,
                                                   unsigned int* __restrict__ Thr,
                                                   unsigned int* __restrict__ cnt)
{
#pragma clang fp contract(off)
    int row = blockIdx.x * 256 + threadIdx.x;
    if (row >= N_ROWS) return;
    if (Thr) Thr[row] = 0xFFFFFFFFu;
    if (cnt) cnt[row] = 0u;
    const float* x = feat + (size_t)row * D;
    float Bres[4];
#pragma unroll
    for (int b = 0; b < 4; ++b) {
        const float* q = x + b * 96;
        float v[8][4];
#pragma unroll
        for (int j = 0; j < 8; ++j)
#pragma unroll
            for (int l = 0; l < 4; ++l) {
                float t = q[4 * j + l];
                v[j][l] = t * t;
            }
#pragma unroll
        for (int i = 32; i <= 64; i += 32)
#pragma unroll
            for (int j = 0; j < 8; ++j)
#pragma unroll
                for (int l = 0; l < 4; ++l) {
                    float t = q[i + 4 * j + l];
                    float p = t * t;
                    v[j][l] = v[j][l] + p;
                }
        float c[4];
#pragma unroll
        for (int l = 0; l < 4; ++l)
            c[l] = ((v[0][l] + v[1][l]) + (v[2][l] + v[3][l]))
                 + ((v[4][l] + v[5][l]) + (v[6][l] + v[7][l]));
        Bres[b] = (c[0] + c[1]) + (c[2] + c[3]);
    }
    float s = (Bres[0] + Bres[1]) + (Bres[2] + Bres[3]);
    S[row] = s;
    if (Mg) Mg[row] = scalbnf(1.0f, ilogbf(s) - 23) + 1.2e-4f;  // ulp(s) + slack
}

// ---------------- bf16 MFMA scan: seeded threshold + candidate collection -------------
// MODE 0 (seed): tiles 0..23 (3072 codes), atomicMin per-row threshold into Thr.
// MODE 1 (main): all 196 tiles in 8 splits; register running-min (init from Thr);
//                appends codes with v <= runmin + margin. No atomics in steady state.
// Swapped operands: A-frag = codebook, B-frag = features -> thread holds 16 codes x
// 4 rows; per-row reduce is a thread-local fmax tree + 2 cross-lane shuffles.
// Double-buffered LDS; stage(next) issued before compute(cur); one __syncthreads/step.
#define STAGE(BUF, NT, KT)                                                                \
    do {                                                                                  \
        const int nn0_ = (nt0 + (NT)) * 128;                                              \
        _Pragma("unroll")                                                                 \
        for (int q = 0; q < 4; ++q) {                                                     \
            const ushort* fa_ = xb + (size_t)(r0 + rq[q]) * D + (KT) * 64 + lcq[q] * 8;   \
            __builtin_amdgcn_global_load_lds(                                             \
                (const __attribute__((address_space(1))) void*)fa_,                       \
                (__attribute__((address_space(3))) void*)&Ft[BUF][sq[q] * 8], 16, 0, 0);  \
            int code_ = nn0_ + rq[q];                                                     \
            code_ = code_ > K_CODES - 1 ? K_CODES - 1 : code_;                            \
            const ushort* ca_ = cbb + (size_t)code_ * D + (KT) * 64 + lcq[q] * 8;         \
            __builtin_amdgcn_global_load_lds(                                             \
                (const __attribute__((address_space(1))) void*)ca_,                       \
                (__attribute__((address_space(3))) void*)&Ct[BUF][sq[q] * 8], 16, 0, 0);  \
        }                                                                                 \
    } while (0)

template <int MODE>
__global__ __launch_bounds__(256) void mfma_scan(const ushort* __restrict__ xb,
                                                 const ushort* __restrict__ cbb,
                                                 const float* __restrict__ Mg,
                                                 unsigned int* __restrict__ Thr,
                                                 unsigned int* __restrict__ cnt,
                                                 unsigned int* __restrict__ cand)
{
    __shared__ ushort Ft[2][128 * 64];
    __shared__ ushort Ct[2][128 * 64];

    const int tid = threadIdx.x;
    const int sp = blockIdx.x & 7;        // XCD-aligned n-split (bid%8 ~ XCD id)
    const int rt = blockIdx.x >> 3;
    const int nt0 = (MODE == 0) ? sp * 3 : sp * 24 + (sp < 4 ? sp : 4);
    const int ntc = (MODE == 0) ? 3 : 24 + (sp < 4 ? 1 : 0);
    const int r0 = rt * 128;

    const int wave = tid >> 6, lane = tid & 63, ln15 = lane & 15, l16 = lane >> 4;
    const int cw = (wave >> 1) * 64;      // wave's code half
    const int rw = (wave & 1) * 64;       // wave's row half

    int sq[4], rq[4], lcq[4];
#pragma unroll
    for (int q = 0; q < 4; ++q) {
        int s = q * 256 + tid;
        sq[q] = s; rq[q] = s >> 3; lcq[q] = (s & 7) ^ ((s >> 3) & 7);
    }

    float run[4], mg[4];
#pragma unroll
    for (int ni = 0; ni < 4; ++ni) {
        int row = r0 + rw + ni * 16 + ln15;
        mg[ni] = Mg[row];
        run[ni] = (MODE == 0) ? __int_as_float(0x7F800000) : unmono_bits(Thr[row]);
    }

    STAGE(0, 0, 0);
    int cur = 0;

#pragma unroll 1
    for (int nt = 0; nt < ntc; ++nt) {
        const int n0 = (nt0 + nt) * 128;
        f32x4 acc[4][4] = {};
#pragma unroll 1
        for (int kt = 0; kt < 6; ++kt) {
            __syncthreads();              // drains cur-buf DMA (issued a full step ago)
            int nnt = (kt == 5) ? nt + 1 : nt;
            int nkt = (kt == 5) ? 0 : kt + 1;
            if (nnt < ntc) STAGE(cur ^ 1, nnt, nkt);
#pragma unroll
            for (int ks = 0; ks < 2; ++ks) {
                bf16x8 af[4], bfv[4];
#pragma unroll
                for (int mi = 0; mi < 4; ++mi) {
                    int c = cw + mi * 16 + ln15, lc = ks * 4 + l16;
                    af[mi] = *(const bf16x8*)&Ct[cur][c * 64 + ((lc ^ (c & 7)) << 3)];
                }
#pragma unroll
                for (int ni = 0; ni < 4; ++ni) {
                    int r = rw + ni * 16 + ln15, lc = ks * 4 + l16;
                    bfv[ni] = *(const bf16x8*)&Ft[cur][r * 64 + ((lc ^ (r & 7)) << 3)];
                }
#pragma unroll
                for (int mi = 0; mi < 4; ++mi)
#pragma unroll
                    for (int ni = 0; ni < 4; ++ni)
                        acc[mi][ni] = __builtin_amdgcn_mfma_f32_16x16x32_bf16(
                            af[mi], bfv[ni], acc[mi][ni], 0, 0, 0);
            }
            cur ^= 1;
        }
        // epilogue: per-row (ni) min of d = -2*dot  ==  -2 * max(dot)
#pragma unroll
        for (int ni = 0; ni < 4; ++ni) {
            float mx = acc[0][ni][0];
#pragma unroll
            for (int mi = 0; mi < 4; ++mi)
#pragma unroll
                for (int rr = 0; rr < 4; ++rr) mx = fmaxf(mx, acc[mi][ni][rr]);
            mx = fmaxf(mx, __shfl_xor(mx, 16));
            mx = fmaxf(mx, __shfl_xor(mx, 32));
            float vt = -2.0f * mx;
            float rn = fminf(run[ni], vt);
            run[ni] = rn;
            if (MODE == 1 && vt <= rn + mg[ni]) {   // rare: record or near-record tile
                float T = rn + mg[ni];
                int row = r0 + rw + ni * 16 + ln15;
#pragma unroll
                for (int mi = 0; mi < 4; ++mi)
#pragma unroll
                    for (int rr = 0; rr < 4; ++rr) {
                        float v = -2.0f * acc[mi][ni][rr];
                        int c = n0 + cw + mi * 16 + l16 * 4 + rr;
                        if (v <= T && c < K_CODES) {
                            unsigned int idx = atomicAdd(&cnt[row], 1u);
                            if (idx < (unsigned)CAND_CAP)
                                cand[(size_t)row * CAND_CAP + idx] = (unsigned int)c;
                        }
                    }
            }
        }
    }

    if (MODE == 0) {
#pragma unroll
        for (int ni = 0; ni < 4; ++ni) {
            float rm = run[ni];
            rm = fminf(rm, __shfl_xor(rm, 16));
            rm = fminf(rm, __shfl_xor(rm, 32));
            if (l16 == 0) {
                int row = r0 + rw + ni * 16 + ln15;
                atomicMin(&Thr[row], mono_bits(rm));
            }
        }
    }
}

// ---------------- exact fp32 rescore of candidates (verified chain order) -------------
__global__ __launch_bounds__(256) void rescore_kernel(const float* __restrict__ feat,
                                                      const float* __restrict__ cb,
                                                      const float* __restrict__ S,
                                                      const unsigned int* __restrict__ cnt,
                                                      const unsigned int* __restrict__ cand,
                                                      unsigned long long* __restrict__ fkey)
{
    int row = blockIdx.x * 4 + (threadIdx.x >> 6);
    int lane = threadIdx.x & 63;
    unsigned int c = cnt[row];
    if (c > (unsigned)CAND_CAP) return;       // rescue kernel owns this row
    const float* x = feat + (size_t)row * D;
    float s = S[row];
    unsigned long long best = ~0ULL;
#pragma unroll
    for (int base = 0; base < CAND_CAP; base += 64) {
        int ci = base + lane;
        if (ci < (int)c) {
            unsigned int n = cand[(size_t)row * CAND_CAP + ci];
            const float* cr = cb + (size_t)n * D;
            float m = 0.f;
            for (int d = 0; d < D; ++d) m = fmaf(x[d], cr[d], m);
            float dd = s - 2.0f * m;
            unsigned long long key = ((unsigned long long)mono_bits(dd) << 32) | n;
            best = key < best ? key : best;
        }
    }
#pragma unroll
    for (int off = 1; off < 64; off <<= 1) {
        unsigned long long o = __shfl_xor(best, off);
        best = o < best ? o : best;
    }
    if (lane == 0) fkey[row] = best;
}

// ---------------- rescue: full exact scan for overflowed rows (expected: none) --------
__global__ __launch_bounds__(256) void rescue_kernel(const float* __restrict__ feat,
                                                     const float* __restrict__ cb,
                                                     const float* __restrict__ S,
                                                     const unsigned int* __restrict__ cnt,
                                                     unsigned long long* __restrict__ fkey)
{
    __shared__ unsigned long long red[256];
    for (int row = blockIdx.x; row < N_ROWS; row += gridDim.x) {
        if (cnt[row] <= (unsigned)CAND_CAP) continue;
        const float* x = feat + (size_t)row * D;
        float s = S[row];
        unsigned long long best = ~0ULL;
        for (int nb = threadIdx.x * 4; nb < K_CODES; nb += 1024) {
            float m[4] = {0.f, 0.f, 0.f, 0.f};
            for (int d = 0; d < D; ++d) {
                float xv = x[d];
#pragma unroll
                for (int j = 0; j < 4; ++j)
                    if (nb + j < K_CODES) m[j] = fmaf(xv, cb[(size_t)(nb + j) * D + d], m[j]);
            }
#pragma unroll
            for (int j = 0; j < 4; ++j)
                if (nb + j < K_CODES) {
                    float dd = s - 2.0f * m[j];
                    unsigned long long key =
                        ((unsigned long long)mono_bits(dd) << 32) | (unsigned)(nb + j);
                    best = key < best ? key : best;
                }
        }
        red[threadIdx.x] = best;
        __syncthreads();
        for (int st = 128; st > 0; st >>= 1) {
            if (threadIdx.x < st)
                if (red[threadIdx.x + st] < red[threadIdx.x]) red[threadIdx.x] = red[threadIdx.x + st];
            __syncthreads();
        }
        if (threadIdx.x == 0) fkey[row] = red[0];
        __syncthreads();
    }
}

// ---------------- fallback (round-2 proven fp32 path) ---------------------------------
__global__ __launch_bounds__(256) void gemm_argmin_fb(const float* __restrict__ feat,
                                                      const float* __restrict__ cb,
                                                      const float* __restrict__ S,
                                                      unsigned long long* __restrict__ keys)
{
    __shared__ float4 A4[64][16];
    __shared__ float4 B4[64][16];
    const int tid = threadIdx.x;
    const int tr = tid & 15;
    const int tk = tid >> 4;
    const int rt = blockIdx.x & 127;
    const int ks = blockIdx.x >> 7;
    const int r0 = rt * 64;
    const int kbase = ks * 6250;
    float s_reg[4];
#pragma unroll
    for (int i = 0; i < 4; ++i) s_reg[i] = S[r0 + 4 * tr + i];
    unsigned long long best[4];
#pragma unroll
    for (int i = 0; i < 4; ++i) best[i] = ~0ULL;
    for (int kt = 0; kt < 98; ++kt) {
        const int k0 = kbase + kt * 64;
        float acc[4][4];
#pragma unroll
        for (int ii = 0; ii < 4; ++ii)
#pragma unroll
            for (int jj = 0; jj < 4; ++jj) acc[ii][jj] = 0.f;
        for (int dc = 0; dc < 6; ++dc) {
            __syncthreads();
#pragma unroll
            for (int t = 0; t < 4; ++t) {
                int fidx = t * 256 + tid;
                int r = fidx >> 4;
                int c4 = fidx & 15;
                const float4* asrc = reinterpret_cast<const float4*>(feat + (size_t)(r0 + r) * D + dc * 64);
                A4[r][c4 ^ ((r >> 2) & 7)] = asrc[c4];
                int k = k0 + r;
                float4 bval = make_float4(0.f, 0.f, 0.f, 0.f);
                if (k < K_CODES) {
                    const float4* bsrc = reinterpret_cast<const float4*>(cb + (size_t)k * D + dc * 64);
                    bval = bsrc[c4];
                }
                B4[r][c4 ^ ((r >> 2) & 7)] = bval;
            }
            __syncthreads();
#pragma unroll 4
            for (int dk4 = 0; dk4 < 16; ++dk4) {
                float4 av[4], bv[4];
#pragma unroll
                for (int i = 0; i < 4; ++i) av[i] = A4[4 * tr + i][dk4 ^ (tr & 7)];
#pragma unroll
                for (int i = 0; i < 4; ++i) bv[i] = B4[4 * tk + i][dk4 ^ (tk & 7)];
#pragma unroll
                for (int ri = 0; ri < 4; ++ri)
#pragma unroll
                    for (int ki = 0; ki < 4; ++ki) {
                        acc[ri][ki] = fmaf(av[ri].x, bv[ki].x, acc[ri][ki]);
                        acc[ri][ki] = fmaf(av[ri].y, bv[ki].y, acc[ri][ki]);
                        acc[ri][ki] = fmaf(av[ri].z, bv[ki].z, acc[ri][ki]);
                        acc[ri][ki] = fmaf(av[ri].w, bv[ki].w, acc[ri][ki]);
                    }
            }
        }
#pragma unroll
        for (int ri = 0; ri < 4; ++ri)
#pragma unroll
            for (int ki = 0; ki < 4; ++ki) {
                int k = k0 + 4 * tk + ki;
                if (k < K_CODES) {
                    float d = s_reg[ri] - 2.0f * acc[ri][ki];
                    unsigned long long key =
                        ((unsigned long long)mono_bits(d) << 32) | (unsigned long long)(unsigned)k;
                    best[ri] = key < best[ri] ? key : best[ri];
                }
            }
    }
#pragma unroll
    for (int ri = 0; ri < 4; ++ri)
        atomicMin(&keys[r0 + 4 * tr + ri], best[ri]);
}

__global__ __launch_bounds__(256) void initkeys_kernel(unsigned long long* __restrict__ keys)
{
    int r = blockIdx.x * 256 + threadIdx.x;
    if (r < N_ROWS) keys[r] = ~0ULL;
}

// ---------------- output kernels -------------------------------------------------------
__global__ __launch_bounds__(256) void finalize_kernel(const unsigned long long* __restrict__ keys,
                                                       float* __restrict__ out)
{
    int r = blockIdx.x * 256 + threadIdx.x;
    if (r < N_ROWS) out[r] = (float)(unsigned int)(keys[r] & 0xFFFFFFFFULL);
}
__global__ __launch_bounds__(256) void copyfeat_kernel(const float4* __restrict__ src,
                                                       float4* __restrict__ dst, int n4)
{
    int i = blockIdx.x * 256 + threadIdx.x;
    if (i < n4) dst[i] = src[i];
}

extern "C" void kernel_launch(void* const* d_in, const int* in_sizes, int n_in,
                              void* d_out, int out_size, void* d_ws, size_t ws_size,
                              hipStream_t stream)
{
    const float* feat = (const float*)d_in[0];   // [8192, 384]
    const float* cb   = (const float*)d_in[1];   // [25000, 384]
    float* out = (float*)d_out;

    char* ws = (char*)d_ws;

    if (ws_size >= WS_NEED) {
        ushort* xb  = (ushort*)(ws + WS_XB);
        ushort* cbb = (ushort*)(ws + WS_CBB);
        unsigned int* cand = (unsigned int*)(ws + WS_CAND);
        unsigned long long* fkey = (unsigned long long*)(ws + WS_FKEY);
        float* S   = (float*)(ws + WS_S);
        float* Mg  = (float*)(ws + WS_MG);
        unsigned int* Thr = (unsigned int*)(ws + WS_THR);
        unsigned int* cnt = (unsigned int*)(ws + WS_CNT);

        cvt_bf16_kernel<<<3072, 256, 0, stream>>>((const float4*)feat, (ushort4*)xb,
                                                  N_ROWS * D / 4);
        cvt_bf16_kernel<<<9375, 256, 0, stream>>>((const float4*)cb, (ushort4*)cbb,
                                                  K_CODES * D / 4);
        prep_kernel<<<N_ROWS / 256, 256, 0, stream>>>(feat, S, Mg, Thr, cnt);
        mfma_scan<0><<<512, 256, 0, stream>>>(xb, cbb, Mg, Thr, cnt, cand);  // seed 3072 codes
        mfma_scan<1><<<512, 256, 0, stream>>>(xb, cbb, Mg, Thr, cnt, cand);  // full scan
        rescore_kernel<<<N_ROWS / 4, 256, 0, stream>>>(feat, cb, S, cnt, cand, fkey);
        rescue_kernel<<<256, 256, 0, stream>>>(feat, cb, S, cnt, fkey);
        finalize_kernel<<<N_ROWS / 256, 256, 0, stream>>>(fkey, out);
    } else {
        unsigned long long* keys = (unsigned long long*)ws;
        float* S = (float*)(ws + 65536);
        initkeys_kernel<<<N_ROWS / 256, 256, 0, stream>>>(keys);
        prep_kernel<<<N_ROWS / 256, 256, 0, stream>>>(feat, S, nullptr, nullptr, nullptr);
        gemm_argmin_fb<<<128 * 4, 256, 0, stream>>>(feat, cb, S, keys);
        finalize_kernel<<<N_ROWS / 256, 256, 0, stream>>>(keys, out);
    }
    copyfeat_kernel<<<(N_ROWS * D / 4) / 256, 256, 0, stream>>>(
        (const float4*)feat, (float4*)(out + N_ROWS), N_ROWS * D / 4);
}